// Round 8
// baseline (565.620 us; speedup 1.0000x reference)
//
#include <hip/hip_runtime.h>
#include <math.h>

// Problem constants (from reference): B=2, A=1152, DET=736, N=512.
// ws layout (floats):
//   [0, 736)                    : h filter taps
//   [736 + b*3056, +3056)       : per-batch {sin/cos interleaved(2304), det-weights(736), scalars(16)}
//   [6848, +B*A*DET*2)          : pair texture, float2 per (b,a,j) = (f[j], f[j+1])
//   [6848 + B*A*DET*2, ...)     : partial sums [NSPLIT][B][512*512]
#define PB_SIZE 3056
#define W_OFF   2304
#define S_OFF   3040
#define NSPLIT  2

__global__ void prep_kernel(const float* __restrict__ angles,
                            const float* __restrict__ dso,
                            const float* __restrict__ ddo,
                            const float* __restrict__ du,
                            const float* __restrict__ hu,
                            float* __restrict__ ws, int nang, int ndet, int B)
{
    int b = blockIdx.x;
    int t = threadIdx.x;
    const float vox = 1.0f / 0.7f;
    float dsov = dso[b];
    float dso_s = vox * dsov;
    float sd_s  = vox * (dsov + ddo[b]);
    float du_s  = vox * du[b];
    float du_v  = du_s * dso_s / sd_s;
    float beta0 = angles[(size_t)b * nang];
    float dbeta = angles[(size_t)b * nang + 1] - beta0;
    float center = 0.5f * (float)(ndet - 1);

    for (int d = t; d < ndet; d += blockDim.x) {
        float v = 0.0f;
        if (d == 0) v = 0.5f;
        else if (d & 1) {
            float pd = 3.14159265358979323846f * (float)d;
            v = -2.0f / (pd * pd);
        }
        ws[d] = v;
    }

    float* pb = ws + 736 + b * PB_SIZE;
    for (int i = t; i < nang; i += blockDim.x) {
        float beta = beta0 + dbeta * (float)i;
        pb[2 * i]     = sinf(beta);
        pb[2 * i + 1] = cosf(beta);
    }
    float* w = pb + W_OFF;
    for (int j = t; j < ndet; j += blockDim.x) {
        float uk = ((float)j - center) * du_v;
        float cosw = dso_s / sqrtf(dso_s * dso_s + uk * uk);
        w[j] = vox * cosw / du_v;
    }
    if (t == 0) {
        float hu0 = fabsf(hu[b]);
        if (hu0 < 1e-6f) hu0 = 1e-6f;
        float* s = pb + S_OFF;
        s[0] = dso_s;
        s[1] = dso_s / du_v;
        s[2] = center;
        s[3] = 1000.0f * 0.5f * dbeta / (hu0 + 1e-6f);
        s[4] = -1000.0f * hu0 / (hu0 + 1e-6f);
        if (b == 0) {
            int same = 0;
            if (B == 2) {
                same = (dso[0] == dso[1]) && (ddo[0] == ddo[1]) && (du[0] == du[1]) &&
                       (angles[0] == angles[nang]) && (angles[1] == angles[nang + 1]);
            }
            s[5] = (float)same;
        }
    }
}

// One block per (angle, batch) row: direct symmetric ramp convolution in LDS,
// then emit a PAIR texture: pairs[j] = (f[j], f[j+1]) with right-edge replicate
// (exactly reproduces the reference's clamped bilinear fetch).
__global__ __launch_bounds__(256) void filter_kernel(const float* __restrict__ sino,
                                                     const float* __restrict__ ws,
                                                     float2* __restrict__ pairs,
                                                     int nang, int ndet)
{
    __shared__ float row[3 * 736];
    __shared__ float hl[736];
    __shared__ float fout[744];   // 737 used
    int a = blockIdx.x;
    int b = blockIdx.y;
    int t = threadIdx.x;
    const float* srow = sino + ((size_t)b * nang + a) * (size_t)ndet;
    const float* wtab = ws + 736 + b * PB_SIZE + W_OFF;

    for (int i = t; i < 736; i += 256) {
        row[i] = 0.0f;
        row[1472 + i] = 0.0f;
    }
    for (int j = t; j < ndet; j += 256)
        row[736 + j] = srow[j] * wtab[j];
    for (int d = t; d < 736; d += 256)
        hl[d] = ws[d];
    __syncthreads();

    for (int i = t; i < ndet; i += 256) {
        const float* rp = row + 736 + i;
        float acc = 0.5f * rp[0];
        #pragma unroll 4
        for (int d = 1; d < 736; d += 2) {
            acc += hl[d] * (rp[-d] + rp[d]);
        }
        fout[i] = acc;
    }
    __syncthreads();
    if (t == 0) fout[ndet] = fout[ndet - 1];
    __syncthreads();

    float2* prow = pairs + ((size_t)b * nang + a) * (size_t)ndet;
    for (int j = t; j < ndet; j += 256)
        prow[j] = make_float2(fout[j], fout[j + 1]);
}

// 16x16 pixel tile per block; blockIdx.z = angle slice (NSPLIT slices for
// occupancy). Fused path: one geometry evaluation per angle feeds ONE float2
// gather per batch. Writes per-slice partial sums; combine_kernel reduces.
__global__ __launch_bounds__(256) void backproject_fused(const float* __restrict__ ws,
                                                         const float2* __restrict__ pairs,
                                                         float* __restrict__ partial,
                                                         int nang, int ndet, int B)
{
    __shared__ float sc[2304];
    int tid = threadIdx.y * 16 + threadIdx.x;
    int cx = blockIdx.x * 16 + threadIdx.x;
    int cy = blockIdx.y * 16 + threadIdx.y;
    int z  = blockIdx.z;
    float X = (float)cx - 255.5f;
    float Y = (float)cy - 255.5f;

    int na_s = (nang + NSPLIT - 1) / NSPLIT;
    int a0 = z * na_s;
    int a1 = min(nang, a0 + na_s);
    int nas = a1 - a0;

    const float* pb0 = ws + 736;
    const float* sp0 = pb0 + S_OFF;
    int fused = (sp0[5] != 0.0f);
    int px = cy * 512 + cx;

    if (fused) {
        for (int i = tid; i < 2 * nas; i += 256)
            sc[i] = pb0[2 * a0 + i];
        __syncthreads();
        float dso_s = sp0[0];
        float k1    = sp0[1];
        float hc    = sp0[2];
        float Xk = X * k1;
        float Yk = Y * k1;
        const float2* pr0 = pairs + (size_t)a0 * ndet;
        const float2* pr1 = pairs + (size_t)(nang + a0) * ndet;
        float acc0 = 0.0f, acc1 = 0.0f;
        int rowoff = 0;
        #pragma unroll 2
        for (int a = 0; a < nas; ++a, rowoff += ndet) {
            float s = sc[2 * a];
            float c = sc[2 * a + 1];
            float U = fmaf(X, s, dso_s) - Y * c;      // > 0 for this geometry
            float r = __builtin_amdgcn_rcpf(U);
            float ts = fmaf(Xk, c, Yk * s);
            float v  = ts * r;                         // u - center
            float u  = v + hc;
            float fi = floorf(u);
            float w  = u - fi;
            int i0   = (int)fi;
            int i0c  = min(max(i0, 0), ndet - 1);
            float2 p0 = pr0[rowoff + i0c];
            float2 p1 = pr1[rowoff + i0c];
            float d  = dso_s * r;
            float wt = d * d;
            wt = (fabsf(v) <= hc) ? wt : 0.0f;
            acc0 = fmaf(fmaf(p0.y - p0.x, w, p0.x), wt, acc0);
            acc1 = fmaf(fmaf(p1.y - p1.x, w, p1.x), wt, acc1);
        }
        partial[(size_t)(z * B + 0) * 262144 + px] = acc0;
        partial[(size_t)(z * B + 1) * 262144 + px] = acc1;
    } else {
        for (int b = 0; b < B; ++b) {
            const float* pb = ws + 736 + b * PB_SIZE;
            const float* sp = pb + S_OFF;
            __syncthreads();
            for (int i = tid; i < 2 * nas; i += 256)
                sc[i] = pb[2 * a0 + i];
            __syncthreads();
            float dso_s = sp[0];
            float k1    = sp[1];
            float hc    = sp[2];
            const float2* pr = pairs + (size_t)(b * nang + a0) * ndet;
            float acc = 0.0f;
            int rowoff = 0;
            for (int a = 0; a < nas; ++a, rowoff += ndet) {
                float s = sc[2 * a];
                float c = sc[2 * a + 1];
                float U = fmaf(X, s, dso_s) - Y * c;
                float r = __builtin_amdgcn_rcpf(U);
                float ts = k1 * fmaf(X, c, Y * s);
                float v  = ts * r;
                float u  = v + hc;
                float fi = floorf(u);
                float w  = u - fi;
                int i0   = (int)fi;
                int i0c  = min(max(i0, 0), ndet - 1);
                float2 p = pr[rowoff + i0c];
                float d  = dso_s * r;
                float wt = d * d;
                wt = (fabsf(v) <= hc) ? wt : 0.0f;
                acc = fmaf(fmaf(p.y - p.x, w, p.x), wt, acc);
            }
            partial[(size_t)(z * B + b) * 262144 + px] = acc;
        }
    }
}

// Sum the NSPLIT partial images and apply the per-batch affine HU transform.
__global__ __launch_bounds__(256) void combine_kernel(const float* __restrict__ partial,
                                                      const float* __restrict__ ws,
                                                      float* __restrict__ out, int B)
{
    int idx = blockIdx.x * 256 + threadIdx.x;   // [0, B*262144)
    int bb = idx >> 18;
    int px = idx & 262143;
    const float* sp = ws + 736 + bb * PB_SIZE + S_OFF;
    float v = 0.0f;
    #pragma unroll
    for (int z = 0; z < NSPLIT; ++z)
        v += partial[(size_t)(z * B + bb) * 262144 + px];
    out[idx] = fmaf(sp[3], v, sp[4]);
}

extern "C" void kernel_launch(void* const* d_in, const int* in_sizes, int n_in,
                              void* d_out, int out_size, void* d_ws, size_t ws_size,
                              hipStream_t stream)
{
    const float* sino   = (const float*)d_in[0];
    const float* angles = (const float*)d_in[1];
    const float* dso    = (const float*)d_in[2];
    const float* ddo    = (const float*)d_in[3];
    const float* du     = (const float*)d_in[4];
    const float* hu     = (const float*)d_in[5];
    float* ws  = (float*)d_ws;
    float* out = (float*)d_out;

    int B    = in_sizes[2];
    int nang = in_sizes[1] / B;
    int ndet = in_sizes[0] / (B * nang);

    float2* pairs   = (float2*)(ws + 736 + B * PB_SIZE);
    float*  partial = ws + 736 + B * PB_SIZE + (size_t)B * nang * ndet * 2;

    prep_kernel<<<B, 256, 0, stream>>>(angles, dso, ddo, du, hu, ws, nang, ndet, B);
    filter_kernel<<<dim3(nang, B), 256, 0, stream>>>(sino, ws, pairs, nang, ndet);
    backproject_fused<<<dim3(32, 32, NSPLIT), dim3(16, 16), 0, stream>>>(
        ws, pairs, partial, nang, ndet, B);
    combine_kernel<<<(B * 262144) / 256, 256, 0, stream>>>(partial, ws, out, B);
}

// Round 10
// 516.377 us; speedup vs baseline: 1.0954x; 1.0954x over previous
//
#include <hip/hip_runtime.h>
#include <math.h>

// Problem constants (from reference): B=2, A=1152, DET=736, N=512.
// ws layout (floats):
//   [0, 736)                  : h filter taps
//   [736 + b*3056, +3056)     : per-batch {sin/cos interleaved(2304), det-weights(736), scalars(16)}
//   [736 + B*3056, ...)       : filtered sinogram [B][A][DET]
#define PB_SIZE 3056
#define W_OFF   2304
#define S_OFF   3040

__global__ void prep_kernel(const float* __restrict__ angles,
                            const float* __restrict__ dso,
                            const float* __restrict__ ddo,
                            const float* __restrict__ du,
                            const float* __restrict__ hu,
                            float* __restrict__ ws, int nang, int ndet, int B)
{
    int b = blockIdx.x;
    int t = threadIdx.x;
    const float vox = 1.0f / 0.7f;
    float dsov = dso[b];
    float dso_s = vox * dsov;
    float sd_s  = vox * (dsov + ddo[b]);
    float du_s  = vox * du[b];
    float du_v  = du_s * dso_s / sd_s;
    float beta0 = angles[(size_t)b * nang];
    float dbeta = angles[(size_t)b * nang + 1] - beta0;
    float center = 0.5f * (float)(ndet - 1);

    for (int d = t; d < ndet; d += blockDim.x) {
        float v = 0.0f;
        if (d == 0) v = 0.5f;
        else if (d & 1) {
            float pd = 3.14159265358979323846f * (float)d;
            v = -2.0f / (pd * pd);
        }
        ws[d] = v;
    }

    float* pb = ws + 736 + b * PB_SIZE;
    for (int i = t; i < nang; i += blockDim.x) {
        float beta = beta0 + dbeta * (float)i;
        pb[2 * i]     = sinf(beta);
        pb[2 * i + 1] = cosf(beta);
    }
    float* w = pb + W_OFF;
    for (int j = t; j < ndet; j += blockDim.x) {
        float uk = ((float)j - center) * du_v;
        float cosw = dso_s / sqrtf(dso_s * dso_s + uk * uk);
        w[j] = vox * cosw / du_v;
    }
    if (t == 0) {
        float hu0 = fabsf(hu[b]);
        if (hu0 < 1e-6f) hu0 = 1e-6f;
        float* s = pb + S_OFF;
        s[0] = dso_s;
        s[1] = dso_s / du_v;
        s[2] = center;
        s[3] = 1000.0f * 0.5f * dbeta / (hu0 + 1e-6f);
        s[4] = -1000.0f * hu0 / (hu0 + 1e-6f);
        if (b == 0) {
            int same = 0;
            if (B == 2) {
                same = (dso[0] == dso[1]) && (ddo[0] == ddo[1]) && (du[0] == du[1]) &&
                       (angles[0] == angles[nang]) && (angles[1] == angles[nang + 1]);
            }
            s[5] = (float)same;
        }
    }
}

// One block per (angle, batch) row: weighted row staged in LDS (zero-padded both
// sides), then direct symmetric convolution with the odd-tap ramp kernel.
__global__ __launch_bounds__(256) void filter_kernel(const float* __restrict__ sino,
                                                     const float* __restrict__ ws,
                                                     float* __restrict__ filtered,
                                                     int nang, int ndet)
{
    __shared__ float row[3 * 736];
    __shared__ float hl[736];
    int a = blockIdx.x;
    int b = blockIdx.y;
    int t = threadIdx.x;
    const float* srow = sino + ((size_t)b * nang + a) * (size_t)ndet;
    const float* wtab = ws + 736 + b * PB_SIZE + W_OFF;

    for (int i = t; i < 736; i += 256) {
        row[i] = 0.0f;
        row[1472 + i] = 0.0f;
    }
    for (int j = t; j < ndet; j += 256)
        row[736 + j] = srow[j] * wtab[j];
    for (int d = t; d < 736; d += 256)
        hl[d] = ws[d];
    __syncthreads();

    float* frow = filtered + ((size_t)b * nang + a) * (size_t)ndet;
    for (int i = t; i < ndet; i += 256) {
        const float* rp = row + 736 + i;
        float acc = 0.5f * rp[0];
        #pragma unroll 4
        for (int d = 1; d < 736; d += 2) {
            acc += hl[d] * (rp[-d] + rp[d]);
        }
        frow[i] = acc;
    }
}

// 16x8 pixel tile per 128-thread block (2 waves), grid 32x64 = 2048 blocks ->
// up to 16 blocks/CU (no LDS, ~32 VGPR) = 32 waves/CU for latency hiding.
// Fused path: one geometry evaluation per angle feeds both batches' bilinear
// gathers. sin/cos read via uniform-index scalar loads (no LDS, no barriers).
__global__ __launch_bounds__(128) void backproject_fused(const float* __restrict__ ws,
                                                         const float* __restrict__ filtered,
                                                         float* __restrict__ out,
                                                         int nang, int ndet, int B)
{
    int cx = blockIdx.x * 16 + threadIdx.x;
    int cy = blockIdx.y * 8 + threadIdx.y;
    float X = (float)cx - 255.5f;
    float Y = (float)cy - 255.5f;

    const float* pb0 = ws + 736;
    const float* sp0 = pb0 + S_OFF;
    int fused = (sp0[5] != 0.0f);
    int px = cy * 512 + cx;

    if (fused) {
        float dso_s = sp0[0];
        float k1    = sp0[1];
        float hc    = sp0[2];            // center == (ndet-1)/2 == half valid range
        const float* sp1 = sp0 + PB_SIZE;
        float Xk = X * k1;
        float Yk = Y * k1;
        const float2* scp = (const float2*)pb0;   // uniform index -> s_load
        const float* fb0 = filtered;
        const float* fb1 = filtered + (size_t)nang * ndet;
        float acc0 = 0.0f, acc1 = 0.0f;
        int rowoff = 0;
        #pragma unroll 2
        for (int a = 0; a < nang; ++a, rowoff += ndet) {
            float2 sc2 = scp[a];
            float s = sc2.x, c = sc2.y;
            float U = fmaf(-Y, c, fmaf(X, s, dso_s));   // > 0 for this geometry
            float r = __builtin_amdgcn_rcpf(U);
            float ts = fmaf(Xk, c, Yk * s);
            float v  = ts * r;                           // u - center
            float u  = v + hc;
            float fi = floorf(u);
            float w  = u - fi;
            int i0   = (int)fi;
            int i0c  = min(max(i0, 0), ndet - 1);
            int i1c  = min(i0c + 1, ndet - 1);           // exact: invalid region zeroed
            const float* r0 = fb0 + rowoff;
            const float* r1 = fb1 + rowoff;
            float q00 = r0[i0c];
            float q01 = r0[i1c];
            float q10 = r1[i0c];
            float q11 = r1[i1c];
            float d  = dso_s * r;
            float wt = d * d;
            wt = (fabsf(v) <= hc) ? wt : 0.0f;
            acc0 = fmaf(fmaf(q01 - q00, w, q00), wt, acc0);
            acc1 = fmaf(fmaf(q11 - q10, w, q10), wt, acc1);
        }
        out[px]             = fmaf(sp0[3], acc0, sp0[4]);
        out[px + 512 * 512] = fmaf(sp1[3], acc1, sp1[4]);
    } else {
        for (int b = 0; b < B; ++b) {
            const float* pb = ws + 736 + b * PB_SIZE;
            const float* sp = pb + S_OFF;
            const float2* scp = (const float2*)pb;
            float dso_s = sp[0];
            float k1    = sp[1];
            float hc    = sp[2];
            const float* fb = filtered + (size_t)b * nang * ndet;
            float acc = 0.0f;
            int rowoff = 0;
            for (int a = 0; a < nang; ++a, rowoff += ndet) {
                float2 sc2 = scp[a];
                float s = sc2.x, c = sc2.y;
                float U = fmaf(-Y, c, fmaf(X, s, dso_s));
                float r = __builtin_amdgcn_rcpf(U);
                float ts = k1 * fmaf(X, c, Y * s);
                float v  = ts * r;
                float u  = v + hc;
                float fi = floorf(u);
                float w  = u - fi;
                int i0   = (int)fi;
                int i0c  = min(max(i0, 0), ndet - 1);
                int i1c  = min(i0c + 1, ndet - 1);
                const float* fr = fb + rowoff;
                float q0 = fr[i0c];
                float q1 = fr[i1c];
                float d  = dso_s * r;
                float wt = d * d;
                wt = (fabsf(v) <= hc) ? wt : 0.0f;
                acc = fmaf(fmaf(q1 - q0, w, q0), wt, acc);
            }
            out[((size_t)b * 512 + cy) * 512 + cx] = fmaf(sp[3], acc, sp[4]);
        }
    }
}

extern "C" void kernel_launch(void* const* d_in, const int* in_sizes, int n_in,
                              void* d_out, int out_size, void* d_ws, size_t ws_size,
                              hipStream_t stream)
{
    const float* sino   = (const float*)d_in[0];
    const float* angles = (const float*)d_in[1];
    const float* dso    = (const float*)d_in[2];
    const float* ddo    = (const float*)d_in[3];
    const float* du     = (const float*)d_in[4];
    const float* hu     = (const float*)d_in[5];
    float* ws  = (float*)d_ws;
    float* out = (float*)d_out;

    int B    = in_sizes[2];
    int nang = in_sizes[1] / B;
    int ndet = in_sizes[0] / (B * nang);

    float* filtered = ws + 736 + B * PB_SIZE;

    prep_kernel<<<B, 256, 0, stream>>>(angles, dso, ddo, du, hu, ws, nang, ndet, B);
    filter_kernel<<<dim3(nang, B), 256, 0, stream>>>(sino, ws, filtered, nang, ndet);
    backproject_fused<<<dim3(32, 64), dim3(16, 8), 0, stream>>>(
        ws, filtered, out, nang, ndet, B);
}

// Round 16
// 427.490 us; speedup vs baseline: 1.3231x; 1.2079x over previous
//
#include <hip/hip_runtime.h>
#include <math.h>

// Problem constants (from reference): B=2, A=1152, DET=736, N=512.
// ws layout (floats):
//   [0, 736)                  : h filter taps
//   [736 + b*3056, +3056)     : per-batch {sin/cos interleaved(2304), det-weights(736), scalars(16)}
//   [736 + B*3056, +B*A*DET)  : filtered sinogram [B][A][DET]
//   [... , +NSPLIT*B*262144)  : partial sums [NSPLIT][B][512*512]
#define PB_SIZE 3056
#define W_OFF   2304
#define S_OFF   3040
#define NSPLIT  4

__global__ void prep_kernel(const float* __restrict__ angles,
                            const float* __restrict__ dso,
                            const float* __restrict__ ddo,
                            const float* __restrict__ du,
                            const float* __restrict__ hu,
                            float* __restrict__ ws, int nang, int ndet, int B)
{
    int b = blockIdx.x;
    int t = threadIdx.x;
    const float vox = 1.0f / 0.7f;
    float dsov = dso[b];
    float dso_s = vox * dsov;
    float sd_s  = vox * (dsov + ddo[b]);
    float du_s  = vox * du[b];
    float du_v  = du_s * dso_s / sd_s;
    float beta0 = angles[(size_t)b * nang];
    float dbeta = angles[(size_t)b * nang + 1] - beta0;
    float center = 0.5f * (float)(ndet - 1);

    for (int d = t; d < ndet; d += blockDim.x) {
        float v = 0.0f;
        if (d == 0) v = 0.5f;
        else if (d & 1) {
            float pd = 3.14159265358979323846f * (float)d;
            v = -2.0f / (pd * pd);
        }
        ws[d] = v;
    }

    float* pb = ws + 736 + b * PB_SIZE;
    for (int i = t; i < nang; i += blockDim.x) {
        float beta = beta0 + dbeta * (float)i;
        pb[2 * i]     = sinf(beta);
        pb[2 * i + 1] = cosf(beta);
    }
    float* w = pb + W_OFF;
    for (int j = t; j < ndet; j += blockDim.x) {
        float uk = ((float)j - center) * du_v;
        float cosw = dso_s / sqrtf(dso_s * dso_s + uk * uk);
        w[j] = vox * cosw / du_v;
    }
    if (t == 0) {
        float hu0 = fabsf(hu[b]);
        if (hu0 < 1e-6f) hu0 = 1e-6f;
        float* s = pb + S_OFF;
        s[0] = dso_s;
        s[1] = dso_s / du_v;
        s[2] = center;
        s[3] = 1000.0f * 0.5f * dbeta / (hu0 + 1e-6f);
        s[4] = -1000.0f * hu0 / (hu0 + 1e-6f);
        if (b == 0) {
            int same = 0;
            if (B == 2) {
                same = (dso[0] == dso[1]) && (ddo[0] == ddo[1]) && (du[0] == du[1]) &&
                       (angles[0] == angles[nang]) && (angles[1] == angles[nang + 1]);
            }
            s[5] = (float)same;
        }
    }
}

// One block per (angle, batch) row. Register-blocked: thread t computes outputs
// {t, t+256, t+512} in ONE tap-loop pass (3 accumulators share each hl[d] read:
// 7 LDS instr/tap vs 9, and 3x FMA ILP). Zero pads reproduce linear-conv edges.
__global__ __launch_bounds__(256) void filter_kernel(const float* __restrict__ sino,
                                                     const float* __restrict__ ws,
                                                     float* __restrict__ filtered,
                                                     int nang, int ndet)
{
    __shared__ float row[2304];  // [0,736) zero | [736,1472) data | [1472,2304) zero
    __shared__ float hl[736];
    int a = blockIdx.x;
    int b = blockIdx.y;
    int t = threadIdx.x;
    const float* srow = sino + ((size_t)b * nang + a) * (size_t)ndet;
    const float* wtab = ws + 736 + b * PB_SIZE + W_OFF;

    for (int i = t; i < 736; i += 256)
        row[i] = 0.0f;
    for (int i = t; i < 832; i += 256)
        row[1472 + i] = 0.0f;               // zero through index 2303
    for (int j = t; j < ndet; j += 256)
        row[736 + j] = srow[j] * wtab[j];
    for (int d = t; d < 736; d += 256)
        hl[d] = ws[d];
    __syncthreads();

    // Max read: rp2[+735] = 736+255+512+735 = 2238 < 2304. Min read: rp0[-735] = 1.
    const float* rp0 = row + 736 + t;
    const float* rp1 = rp0 + 256;
    const float* rp2 = rp0 + 512;
    float acc0 = 0.5f * rp0[0];
    float acc1 = 0.5f * rp1[0];
    float acc2 = 0.5f * rp2[0];
    #pragma unroll 4
    for (int d = 1; d < 736; d += 2) {
        float h = hl[d];
        acc0 = fmaf(h, rp0[-d] + rp0[d], acc0);
        acc1 = fmaf(h, rp1[-d] + rp1[d], acc1);
        acc2 = fmaf(h, rp2[-d] + rp2[d], acc2);
    }
    float* frow = filtered + ((size_t)b * nang + a) * (size_t)ndet;
    frow[t]       = acc0;
    frow[t + 256] = acc1;
    if (t < ndet - 512)
        frow[t + 512] = acc2;
}

// 16x16 pixel tile per block; blockIdx.z = angle slice (NSPLIT slices so the
// grid has 16384 waves > 8192 chip capacity -> occupancy not grid-capped).
// Fused path: one geometry evaluation per angle feeds both batches' bilinear
// gathers (4 plain 4B loads, 6.8MB L2-resident footprint). sin/cos from a
// per-slice LDS table (round-6-proven; pipelines better than s_load).
__global__ __launch_bounds__(256) void backproject_fused(const float* __restrict__ ws,
                                                         const float* __restrict__ filtered,
                                                         float* __restrict__ partial,
                                                         int nang, int ndet, int B)
{
    __shared__ float sc[2 * ((1152 + NSPLIT - 1) / NSPLIT)];
    int tid = threadIdx.y * 16 + threadIdx.x;
    int cx = blockIdx.x * 16 + threadIdx.x;
    int cy = blockIdx.y * 16 + threadIdx.y;
    int z  = blockIdx.z;
    float X = (float)cx - 255.5f;
    float Y = (float)cy - 255.5f;

    int na_s = (nang + NSPLIT - 1) / NSPLIT;
    int a0 = z * na_s;
    int a1 = min(nang, a0 + na_s);
    int nas = a1 - a0;

    const float* pb0 = ws + 736;
    const float* sp0 = pb0 + S_OFF;
    int fused = (sp0[5] != 0.0f);
    int px = cy * 512 + cx;

    if (fused) {
        for (int i = tid; i < 2 * nas; i += 256)
            sc[i] = pb0[2 * a0 + i];
        __syncthreads();
        float dso_s = sp0[0];
        float k1    = sp0[1];
        float hc    = sp0[2];            // center == (ndet-1)/2 == half valid range
        float Xk = X * k1;
        float Yk = Y * k1;
        const float* fb0 = filtered + (size_t)a0 * ndet;
        const float* fb1 = filtered + (size_t)(nang + a0) * ndet;
        float acc0 = 0.0f, acc1 = 0.0f;
        int rowoff = 0;
        #pragma unroll 2
        for (int a = 0; a < nas; ++a, rowoff += ndet) {
            float s = sc[2 * a];
            float c = sc[2 * a + 1];
            float U = fmaf(-Y, c, fmaf(X, s, dso_s));   // > 0 for this geometry
            float r = __builtin_amdgcn_rcpf(U);
            float ts = fmaf(Xk, c, Yk * s);
            float v  = ts * r;                           // u - center
            float u  = v + hc;
            float fi = floorf(u);
            float w  = u - fi;
            int i0   = (int)fi;
            int i0c  = min(max(i0, 0), ndet - 1);
            int i1c  = min(i0c + 1, ndet - 1);           // exact: invalid region zeroed
            const float* r0 = fb0 + rowoff;
            const float* r1 = fb1 + rowoff;
            float q00 = r0[i0c];
            float q01 = r0[i1c];
            float q10 = r1[i0c];
            float q11 = r1[i1c];
            float d  = dso_s * r;
            float wt = d * d;
            wt = (fabsf(v) <= hc) ? wt : 0.0f;
            acc0 = fmaf(fmaf(q01 - q00, w, q00), wt, acc0);
            acc1 = fmaf(fmaf(q11 - q10, w, q10), wt, acc1);
        }
        partial[(size_t)(z * B + 0) * 262144 + px] = acc0;
        partial[(size_t)(z * B + 1) * 262144 + px] = acc1;
    } else {
        for (int b = 0; b < B; ++b) {
            const float* pb = ws + 736 + b * PB_SIZE;
            const float* sp = pb + S_OFF;
            __syncthreads();
            for (int i = tid; i < 2 * nas; i += 256)
                sc[i] = pb[2 * a0 + i];
            __syncthreads();
            float dso_s = sp[0];
            float k1    = sp[1];
            float hc    = sp[2];
            const float* fb = filtered + ((size_t)b * nang + a0) * ndet;
            float acc = 0.0f;
            int rowoff = 0;
            for (int a = 0; a < nas; ++a, rowoff += ndet) {
                float s = sc[2 * a];
                float c = sc[2 * a + 1];
                float U = fmaf(-Y, c, fmaf(X, s, dso_s));
                float r = __builtin_amdgcn_rcpf(U);
                float ts = k1 * fmaf(X, c, Y * s);
                float v  = ts * r;
                float u  = v + hc;
                float fi = floorf(u);
                float w  = u - fi;
                int i0   = (int)fi;
                int i0c  = min(max(i0, 0), ndet - 1);
                int i1c  = min(i0c + 1, ndet - 1);
                const float* fr = fb + rowoff;
                float q0 = fr[i0c];
                float q1 = fr[i1c];
                float d  = dso_s * r;
                float wt = d * d;
                wt = (fabsf(v) <= hc) ? wt : 0.0f;
                acc = fmaf(fmaf(q1 - q0, w, q0), wt, acc);
            }
            partial[(size_t)(z * B + b) * 262144 + px] = acc;
        }
    }
}

// Sum the NSPLIT partial images and apply the per-batch affine HU transform.
__global__ __launch_bounds__(256) void combine_kernel(const float* __restrict__ partial,
                                                      const float* __restrict__ ws,
                                                      float* __restrict__ out, int B)
{
    int idx = blockIdx.x * 256 + threadIdx.x;   // [0, B*262144)
    int bb = idx >> 18;
    int px = idx & 262143;
    const float* sp = ws + 736 + bb * PB_SIZE + S_OFF;
    float v = 0.0f;
    #pragma unroll
    for (int z = 0; z < NSPLIT; ++z)
        v += partial[(size_t)(z * B + bb) * 262144 + px];
    out[idx] = fmaf(sp[3], v, sp[4]);
}

extern "C" void kernel_launch(void* const* d_in, const int* in_sizes, int n_in,
                              void* d_out, int out_size, void* d_ws, size_t ws_size,
                              hipStream_t stream)
{
    const float* sino   = (const float*)d_in[0];
    const float* angles = (const float*)d_in[1];
    const float* dso    = (const float*)d_in[2];
    const float* ddo    = (const float*)d_in[3];
    const float* du     = (const float*)d_in[4];
    const float* hu     = (const float*)d_in[5];
    float* ws  = (float*)d_ws;
    float* out = (float*)d_out;

    int B    = in_sizes[2];
    int nang = in_sizes[1] / B;
    int ndet = in_sizes[0] / (B * nang);

    float* filtered = ws + 736 + B * PB_SIZE;
    float* partial  = filtered + (size_t)B * nang * ndet;

    prep_kernel<<<B, 256, 0, stream>>>(angles, dso, ddo, du, hu, ws, nang, ndet, B);
    filter_kernel<<<dim3(nang, B), 256, 0, stream>>>(sino, ws, filtered, nang, ndet);
    backproject_fused<<<dim3(32, 32, NSPLIT), dim3(16, 16), 0, stream>>>(
        ws, filtered, partial, nang, ndet, B);
    combine_kernel<<<(B * 262144) / 256, 256, 0, stream>>>(partial, ws, out, B);
}